// Round 5
// baseline (176.423 us; speedup 1.0000x reference)
//
#include <hip/hip_runtime.h>

// PPO loss fused pipeline for MI355X (gfx950).
// R4: k_mlp = 512 blocks x 1024 thr (16 waves, 4/EU), wave tile 32x64
// (acc=32 VGPR, no spill; R3 spilled at 64x64). A/B MFMA fragments loaded
// DIRECTLY from global (L2/L3-hot) -> zero barriers in GEMM loops; LDS only
// for hidden1/hidden2 handoff (smH1+smH2, 128KB).

#define TT 65536

typedef float f32x4 __attribute__((ext_vector_type(4)));
typedef __bf16 bf16x8 __attribute__((ext_vector_type(8)));
typedef unsigned short u16x8 __attribute__((ext_vector_type(8)));

__device__ __forceinline__ unsigned short f2bf(float f) {
    unsigned int u = __float_as_uint(f);
    unsigned int r = (u + 0x7fffu + ((u >> 16) & 1u)) >> 16;
    return (unsigned short)r;
}

// branch-free tanh: 1 - 2/(e^{2x}+1)
__device__ __forceinline__ float fast_tanh(float x) {
    float e = __expf(2.0f * x);
    return fmaf(-2.0f, __builtin_amdgcn_rcpf(e + 1.0f), 1.0f);
}

// ---------------- GAE affine suffix scan ----------------
__device__ __forceinline__ void suffix_scan256(float* sC, float* sD, int i) {
    float c = sC[i], d = sD[i];
#pragma unroll
    for (int s = 1; s < 256; s <<= 1) {
        float c2 = 1.0f, d2 = 0.0f;
        if (i + s < 256) { c2 = sC[i + s]; d2 = sD[i + s]; }
        __syncthreads();
        d = d + c * d2;
        c = c * c2;
        sC[i] = c; sD[i] = d;
        __syncthreads();
    }
}

__device__ __forceinline__ void gae_cd(const float* rewards, const float* terms,
                                       const float* values, int t, float* c, float* d) {
    float nt = 1.0f - terms[t];
    float nv = (t + 1 < TT) ? values[t + 1] : 0.0f;
    *d = rewards[t] + 0.99f * nv * nt - values[t];
    *c = 0.99f * 0.95f * nt;
}

// ---------------- fused prep + gae1 ----------------
__global__ void k_prep_gae1(const float* __restrict__ W1, const float* __restrict__ W2,
                            const float* __restrict__ Wa, const float* __restrict__ Wc,
                            unsigned short* __restrict__ W1T, unsigned short* __restrict__ W2T,
                            unsigned short* __restrict__ WavT,
                            const float* __restrict__ rewards, const float* __restrict__ terms,
                            const float* __restrict__ values, float* __restrict__ aggC,
                            float* __restrict__ aggD) {
    if (blockIdx.x < 800) {
        int idx = blockIdx.x * 256 + threadIdx.x;
        if (idx < 131072) {
            int n = idx >> 9, k = idx & 511;          // W1T[n][k] = W1[k][n]
            W1T[idx] = f2bf(W1[k * 256 + n]);
        } else if (idx < 196608) {
            int i = idx - 131072;
            int n = i >> 8, k = i & 255;              // W2T[n][k] = W2[k][n]
            W2T[i] = f2bf(W2[k * 256 + n]);
        } else if (idx < 204800) {
            int i = idx - 196608;
            int r = i >> 8, k = i & 255;              // rows 0-15: Wa^T, 16: Wc^T, 17-31: 0
            float v = (r < 16) ? Wa[k * 16 + r] : ((r == 16) ? Wc[k] : 0.0f);
            WavT[i] = f2bf(v);
        }
        return;
    }
    __shared__ float sC[256], sD[256];
    int i = threadIdx.x;
    int b = blockIdx.x - 800;
    int t = b * 256 + i;
    float c, d;
    gae_cd(rewards, terms, values, t, &c, &d);
    sC[i] = c; sD[i] = d;
    __syncthreads();
    suffix_scan256(sC, sD, i);
    if (i == 0) { aggC[b] = sC[0]; aggD[b] = sD[0]; }
}

// ---------------- gae3: carry + adv/ret + per-block sum partials ----------------
__global__ void k_gae3(const float* __restrict__ rewards, const float* __restrict__ terms,
                       const float* __restrict__ values, const float* __restrict__ aggC,
                       const float* __restrict__ aggD, float* __restrict__ adv,
                       float* __restrict__ ret, float* __restrict__ sumP) {
    __shared__ float sC[256], sD[256];
    int i = threadIdx.x, b = blockIdx.x;
    sC[i] = aggC[i]; sD[i] = aggD[i];
    __syncthreads();
    suffix_scan256(sC, sD, i);
    float carry = (b < 255) ? sD[b + 1] : 0.0f;
    __syncthreads();

    int t = b * 256 + i;
    float c, d;
    gae_cd(rewards, terms, values, t, &c, &d);
    sC[i] = c; sD[i] = d;
    __syncthreads();
    suffix_scan256(sC, sD, i);
    float a = sD[i] + sC[i] * carry;
    adv[t] = a;
    ret[t] = a + values[t];
    __syncthreads();
    sC[i] = a; sD[i] = a * a;
    __syncthreads();
#pragma unroll
    for (int s = 128; s > 0; s >>= 1) {
        if (i < s) { sC[i] += sC[i + s]; sD[i] += sD[i + s]; }
        __syncthreads();
    }
    if (i == 0) { sumP[2 * b] = sC[0]; sumP[2 * b + 1] = sD[0]; }
}

// ---------------- fused MLP + heads + loss (128 rows/block, 16 waves) ----------------
// Wave grid 4mw x 4nw; wave tile 32 rows x 64 cols (acc[2][4]).
// A (obs fp32) and B (W1T/W2T/WavT bf16) fragments loaded directly from global.
// smH1/smH2 [128][256] bf16, swizzle: elem' = elem ^ ((row&7)<<3).
__global__ __launch_bounds__(1024, 4) void k_mlp(
    const float* __restrict__ obs, const int* __restrict__ actions,
    const float* __restrict__ logprobs, const float* __restrict__ values,
    const float* __restrict__ b1, const float* __restrict__ b2,
    const float* __restrict__ ba, const float* __restrict__ bc,
    const unsigned short* __restrict__ W1T, const unsigned short* __restrict__ W2T,
    const unsigned short* __restrict__ WavT, const float* __restrict__ adv,
    const float* __restrict__ ret, const float* __restrict__ sumP,
    float* __restrict__ lossP) {
    __shared__ __align__(16) unsigned short smH1[128 * 256];   // 64KB
    __shared__ __align__(16) unsigned short smH2[128 * 256];   // 64KB
    float* red = (float*)smH1;   // stats scratch (dead before epilogue1)

    const int tid = threadIdx.x;
    const int wid = tid >> 6;
    const int lane = tid & 63;
    const int cl = lane & 15;
    const int gg = lane >> 4;
    const int mw = wid >> 2;
    const int nw = wid & 3;
    const int bm0 = blockIdx.x * 128;

    // ---- adv stats (folds gae4) ----
    float meanA, rstdA;
    {
        if (tid < 256) { red[tid] = sumP[2 * tid]; red[256 + tid] = sumP[2 * tid + 1]; }
        __syncthreads();
#pragma unroll
        for (int s = 128; s > 0; s >>= 1) {
            if (tid < s) { red[tid] += red[tid + s]; red[256 + tid] += red[256 + tid + s]; }
            __syncthreads();
        }
        meanA = red[0] * (1.0f / TT);
        float var = red[256] * (1.0f / TT) - meanA * meanA;
        rstdA = 1.0f / (sqrtf(fmaxf(var, 0.0f)) + 1e-8f);
        __syncthreads();   // red reads done before epilogue1 reuses smH1
    }

    float b1v[4], b2v[4];
#pragma unroll
    for (int n = 0; n < 4; ++n) {
        int c = nw * 64 + n * 16 + cl;
        b1v[n] = b1[c];
        b2v[n] = b2[c];
    }
    const float bav = ba[cl];
    const float bc0 = bc[0];

    f32x4 acc[2][4];
#pragma unroll
    for (int m = 0; m < 2; ++m)
#pragma unroll
        for (int n = 0; n < 4; ++n) acc[m][n] = (f32x4){0.f, 0.f, 0.f, 0.f};

    // ---------------- GEMM1: hidden1 = tanh(obs @ W1 + b1), K=512 ----------------
    // A frag (m): obs[bm0 + mw*32 + m*16 + cl][kt*32 + gg*8 ..+7]  (fp32 -> bf16)
    // B frag (n): W1T[nw*64 + n*16 + cl][kt*32 + gg*8 ..+7]        (bf16)
    {
        const float* aBase = obs + (size_t)(bm0 + mw * 32 + cl) * 512 + gg * 8;
        const unsigned short* bBase = W1T + (size_t)(nw * 64 + cl) * 512 + gg * 8;
#pragma unroll
        for (int kt = 0; kt < 16; ++kt) {
            bf16x8 av[2], bv[4];
#pragma unroll
            for (int m = 0; m < 2; ++m) {
                const float* p = aBase + m * 16 * 512 + kt * 32;
                float4 f0 = *(const float4*)(p);
                float4 f1 = *(const float4*)(p + 4);
                u16x8 cc;
                cc[0] = f2bf(f0.x); cc[1] = f2bf(f0.y); cc[2] = f2bf(f0.z); cc[3] = f2bf(f0.w);
                cc[4] = f2bf(f1.x); cc[5] = f2bf(f1.y); cc[6] = f2bf(f1.z); cc[7] = f2bf(f1.w);
                av[m] = *(bf16x8*)&cc;
            }
#pragma unroll
            for (int n = 0; n < 4; ++n)
                bv[n] = *(const bf16x8*)(bBase + n * 16 * 512 + kt * 32);
#pragma unroll
            for (int m = 0; m < 2; ++m)
#pragma unroll
                for (int n = 0; n < 4; ++n)
                    acc[m][n] = __builtin_amdgcn_mfma_f32_16x16x32_bf16(av[m], bv[n], acc[m][n], 0, 0, 0);
        }
    }

    // epilogue 1: tanh -> smH1 (swizzled), reset acc
#pragma unroll
    for (int m = 0; m < 2; ++m)
#pragma unroll
        for (int n = 0; n < 4; ++n)
#pragma unroll
            for (int j = 0; j < 4; ++j) {
                int r = mw * 32 + m * 16 + gg * 4 + j;
                int c = nw * 64 + n * 16 + cl;
                smH1[r * 256 + (c ^ ((r & 7) << 3))] = f2bf(fast_tanh(acc[m][n][j] + b1v[n]));
                acc[m][n][j] = 0.0f;
            }
    __syncthreads();   // hidden1 complete

    // ---------------- GEMM2: hidden = tanh(hidden1 @ W2 + b2), K=256 ----------------
    {
        const unsigned short* bBase = W2T + (size_t)(nw * 64 + cl) * 256 + gg * 8;
        const int ar0 = mw * 32 + cl;
#pragma unroll
        for (int kt = 0; kt < 8; ++kt) {
            bf16x8 av[2], bv[4];
#pragma unroll
            for (int m = 0; m < 2; ++m) {
                int r = ar0 + m * 16;
                av[m] = *(const bf16x8*)&smH1[r * 256 + ((kt * 32 + gg * 8) ^ ((r & 7) << 3))];
            }
#pragma unroll
            for (int n = 0; n < 4; ++n)
                bv[n] = *(const bf16x8*)(bBase + n * 16 * 256 + kt * 32);
#pragma unroll
            for (int m = 0; m < 2; ++m)
#pragma unroll
                for (int n = 0; n < 4; ++n)
                    acc[m][n] = __builtin_amdgcn_mfma_f32_16x16x32_bf16(av[m], bv[n], acc[m][n], 0, 0, 0);
        }
    }

    // epilogue 2: hidden -> smH2 (separate buffer; no read/write hazard)
#pragma unroll
    for (int m = 0; m < 2; ++m)
#pragma unroll
        for (int n = 0; n < 4; ++n)
#pragma unroll
            for (int j = 0; j < 4; ++j) {
                int r = mw * 32 + m * 16 + gg * 4 + j;
                int c = nw * 64 + n * 16 + cl;
                smH2[r * 256 + (c ^ ((r & 7) << 3))] = f2bf(fast_tanh(acc[m][n][j] + b2v[n]));
            }
    __syncthreads();   // hidden complete

    // ---------------- heads + loss: waves 0..7, wave wid owns rows [wid*16,+16) ----------------
    float lsum = 0.0f;
    if (wid < 8) {
        f32x4 acc_a = {0.f, 0.f, 0.f, 0.f}, acc_v = {0.f, 0.f, 0.f, 0.f};
        const unsigned short* baA = WavT + (size_t)cl * 256 + gg * 8;          // rows 0-15: Wa^T
        const unsigned short* baV = WavT + (size_t)(16 + cl) * 256 + gg * 8;   // row 16: Wc^T (17-31 zero)
#pragma unroll
        for (int kk = 0; kk < 8; ++kk) {
            int r = wid * 16 + cl;
            bf16x8 av = *(const bf16x8*)&smH2[r * 256 + ((kk * 32 + gg * 8) ^ ((r & 7) << 3))];
            bf16x8 bva = *(const bf16x8*)(baA + kk * 32);
            bf16x8 bvv = *(const bf16x8*)(baV + kk * 32);
            acc_a = __builtin_amdgcn_mfma_f32_16x16x32_bf16(av, bva, acc_a, 0, 0, 0);
            acc_v = __builtin_amdgcn_mfma_f32_16x16x32_bf16(av, bvv, acc_v, 0, 0, 0);
        }

        const int t0 = bm0 + wid * 16;
#pragma unroll
        for (int j = 0; j < 4; ++j) {
            int t = t0 + gg * 4 + j;
            float lg = acc_a[j] + bav;
            float mx = lg;
#pragma unroll
            for (int dd = 1; dd < 16; dd <<= 1) mx = fmaxf(mx, __shfl_xor(mx, dd));
            float ex = __expf(lg - mx);
            float se = ex;
#pragma unroll
            for (int dd = 1; dd < 16; dd <<= 1) se += __shfl_xor(se, dd);
            float ls = __logf(se);
            float lp = lg - mx - ls;
            float pl = __expf(lp) * lp;
            float ent = pl;
#pragma unroll
            for (int dd = 1; dd < 16; dd <<= 1) ent += __shfl_xor(ent, dd);
            ent = -ent;
            int act = actions[t];
            float newlp = __shfl(lp, (lane & 48) | act);
            float val = __shfl(acc_v[j], lane & 48) + bc0;

            float lpo = logprobs[t];
            float at = (adv[t] - meanA) * rstdA;
            float rt = ret[t];
            float vo = values[t];
            float ratio = __expf(newlp - lpo);
            float rcl = fminf(fmaxf(ratio, 0.8f), 1.2f);
            float pg = fmaxf(-at * ratio, -at * rcl);
            float vcl = vo + fminf(fmaxf(val - vo, -0.2f), 0.2f);
            float dv = val - rt, dvc = vcl - rt;
            float vl = fmaxf(dv * dv, dvc * dvc);
            if (cl == 0) lsum += pg - 0.01f * ent + 0.25f * vl;
        }
        lsum += __shfl_xor(lsum, 16);
        lsum += __shfl_xor(lsum, 32);
    }
    __syncthreads();                 // heads' smH2 reads done; smH1 region reusable
    if (wid < 8 && lane == 0) red[wid] = lsum;
    __syncthreads();
    if (tid == 0) {
        float s = 0.0f;
#pragma unroll
        for (int w = 0; w < 8; ++w) s += red[w];
        lossP[blockIdx.x] = s;
    }
}

__global__ void k_final(const float* __restrict__ lossP, float* __restrict__ out) {
    __shared__ float s[256];
    int i = threadIdx.x;
    s[i] = lossP[i] + lossP[i + 256];
    __syncthreads();
#pragma unroll
    for (int st = 128; st > 0; st >>= 1) {
        if (i < st) s[i] += s[i + st];
        __syncthreads();
    }
    if (i == 0) out[0] = s[0] * (1.0f / TT);
}

extern "C" void kernel_launch(void* const* d_in, const int* in_sizes, int n_in,
                              void* d_out, int out_size, void* d_ws, size_t ws_size,
                              hipStream_t stream) {
    const float* obs      = (const float*)d_in[0];
    const int*   actions  = (const int*)d_in[1];
    const float* logprobs = (const float*)d_in[2];
    const float* rewards  = (const float*)d_in[3];
    const float* terms    = (const float*)d_in[4];
    const float* values   = (const float*)d_in[5];
    const float* W1 = (const float*)d_in[6];
    const float* b1 = (const float*)d_in[7];
    const float* W2 = (const float*)d_in[8];
    const float* b2 = (const float*)d_in[9];
    const float* Wa = (const float*)d_in[10];
    const float* ba = (const float*)d_in[11];
    const float* Wc = (const float*)d_in[12];
    const float* bc = (const float*)d_in[13];

    char* ws = (char*)d_ws;
    unsigned short* W1T  = (unsigned short*)(ws + 0);        // 262144 B
    unsigned short* W2T  = (unsigned short*)(ws + 262144);   // 131072 B
    unsigned short* WavT = (unsigned short*)(ws + 393216);   // 16384 B
    float* advp  = (float*)(ws + 409600);                    // 262144 B
    float* retp  = (float*)(ws + 671744);                    // 262144 B
    float* aggC  = (float*)(ws + 933888);                    // 1024 B
    float* aggD  = (float*)(ws + 934912);                    // 1024 B
    float* sumP  = (float*)(ws + 936960);                    // 2048 B
    float* lossP = (float*)(ws + 939072);                    // 2048 B

    k_prep_gae1<<<1056, 256, 0, stream>>>(W1, W2, Wa, Wc, W1T, W2T, WavT,
                                          rewards, terms, values, aggC, aggD);
    k_gae3<<<256, 256, 0, stream>>>(rewards, terms, values, aggC, aggD, advp, retp, sumP);
    k_mlp<<<512, 1024, 0, stream>>>(obs, actions, logprobs, values, b1, b2, ba, bc,
                                    W1T, W2T, WavT, advp, retp, sumP, lossP);
    k_final<<<1, 256, 0, stream>>>(lossP, (float*)d_out);
}

// Round 6
// 73.313 us; speedup vs baseline: 2.4064x; 2.4064x over previous
//
#include <hip/hip_runtime.h>

// PPO loss fused pipeline for MI355X (gfx950).
// R5: k_mlp = 512 blocks x 1024 thr (16 waves, 4/SIMD), wave tile 32x64
// (acc[2][4], no spill per R4). COALESCED reg-staging (T14): global loads
// issued at iter start, ds_write at iter end; no global_load_lds so barriers
// never drain vmcnt. LDS: smA dbuf 16K + smB dbuf 32K + smH 64K = 112KB.

#define TT 65536

typedef float f32x4 __attribute__((ext_vector_type(4)));
typedef __bf16 bf16x8 __attribute__((ext_vector_type(8)));
typedef unsigned short u16x8 __attribute__((ext_vector_type(8)));
typedef unsigned short u16x4 __attribute__((ext_vector_type(4)));

__device__ __forceinline__ unsigned short f2bf(float f) {
    unsigned int u = __float_as_uint(f);
    unsigned int r = (u + 0x7fffu + ((u >> 16) & 1u)) >> 16;
    return (unsigned short)r;
}

// branch-free tanh: 1 - 2/(e^{2x}+1)
__device__ __forceinline__ float fast_tanh(float x) {
    float e = __expf(2.0f * x);
    return fmaf(-2.0f, __builtin_amdgcn_rcpf(e + 1.0f), 1.0f);
}

// ---------------- GAE affine suffix scan ----------------
__device__ __forceinline__ void suffix_scan256(float* sC, float* sD, int i) {
    float c = sC[i], d = sD[i];
#pragma unroll
    for (int s = 1; s < 256; s <<= 1) {
        float c2 = 1.0f, d2 = 0.0f;
        if (i + s < 256) { c2 = sC[i + s]; d2 = sD[i + s]; }
        __syncthreads();
        d = d + c * d2;
        c = c * c2;
        sC[i] = c; sD[i] = d;
        __syncthreads();
    }
}

__device__ __forceinline__ void gae_cd(const float* rewards, const float* terms,
                                       const float* values, int t, float* c, float* d) {
    float nt = 1.0f - terms[t];
    float nv = (t + 1 < TT) ? values[t + 1] : 0.0f;
    *d = rewards[t] + 0.99f * nv * nt - values[t];
    *c = 0.99f * 0.95f * nt;
}

// ---------------- fused prep + gae1 ----------------
__global__ void k_prep_gae1(const float* __restrict__ W1, const float* __restrict__ W2,
                            const float* __restrict__ Wa, const float* __restrict__ Wc,
                            unsigned short* __restrict__ W1T, unsigned short* __restrict__ W2T,
                            unsigned short* __restrict__ WavT,
                            const float* __restrict__ rewards, const float* __restrict__ terms,
                            const float* __restrict__ values, float* __restrict__ aggC,
                            float* __restrict__ aggD) {
    if (blockIdx.x < 800) {
        int idx = blockIdx.x * 256 + threadIdx.x;
        if (idx < 131072) {
            int n = idx >> 9, k = idx & 511;          // W1T[n][k] = W1[k][n]
            W1T[idx] = f2bf(W1[k * 256 + n]);
        } else if (idx < 196608) {
            int i = idx - 131072;
            int n = i >> 8, k = i & 255;              // W2T[n][k] = W2[k][n]
            W2T[i] = f2bf(W2[k * 256 + n]);
        } else if (idx < 204800) {
            int i = idx - 196608;
            int r = i >> 8, k = i & 255;              // rows 0-15: Wa^T, 16: Wc^T, 17-31: 0
            float v = (r < 16) ? Wa[k * 16 + r] : ((r == 16) ? Wc[k] : 0.0f);
            WavT[i] = f2bf(v);
        }
        return;
    }
    __shared__ float sC[256], sD[256];
    int i = threadIdx.x;
    int b = blockIdx.x - 800;
    int t = b * 256 + i;
    float c, d;
    gae_cd(rewards, terms, values, t, &c, &d);
    sC[i] = c; sD[i] = d;
    __syncthreads();
    suffix_scan256(sC, sD, i);
    if (i == 0) { aggC[b] = sC[0]; aggD[b] = sD[0]; }
}

// ---------------- gae3: carry + adv/ret + per-block sum partials ----------------
__global__ void k_gae3(const float* __restrict__ rewards, const float* __restrict__ terms,
                       const float* __restrict__ values, const float* __restrict__ aggC,
                       const float* __restrict__ aggD, float* __restrict__ adv,
                       float* __restrict__ ret, float* __restrict__ sumP) {
    __shared__ float sC[256], sD[256];
    int i = threadIdx.x, b = blockIdx.x;
    sC[i] = aggC[i]; sD[i] = aggD[i];
    __syncthreads();
    suffix_scan256(sC, sD, i);
    float carry = (b < 255) ? sD[b + 1] : 0.0f;
    __syncthreads();

    int t = b * 256 + i;
    float c, d;
    gae_cd(rewards, terms, values, t, &c, &d);
    sC[i] = c; sD[i] = d;
    __syncthreads();
    suffix_scan256(sC, sD, i);
    float a = sD[i] + sC[i] * carry;
    adv[t] = a;
    ret[t] = a + values[t];
    __syncthreads();
    sC[i] = a; sD[i] = a * a;
    __syncthreads();
#pragma unroll
    for (int s = 128; s > 0; s >>= 1) {
        if (i < s) { sC[i] += sC[i + s]; sD[i] += sD[i + s]; }
        __syncthreads();
    }
    if (i == 0) { sumP[2 * b] = sC[0]; sumP[2 * b + 1] = sD[0]; }
}

// ---------------- fused MLP + heads + loss (128 rows/block, 16 waves) ----------------
// Wave grid 4mw x 4nw; wave tile 32 rows x 64 cols (acc[2][4], 32 VGPR).
// Staged tiles [R][32] bf16, swizzle: 16B slot' = slot ^ ((row>>1)&3)
//   (read frags: 16 lanes x 16 consecutive rows -> all 32 banks 2-way = free).
// smH [128][256] bf16, swizzle: elem' = elem ^ ((row&7)<<3).
__global__ __launch_bounds__(1024, 4) void k_mlp(
    const float* __restrict__ obs, const int* __restrict__ actions,
    const float* __restrict__ logprobs, const float* __restrict__ values,
    const float* __restrict__ b1, const float* __restrict__ b2,
    const float* __restrict__ ba, const float* __restrict__ bc,
    const unsigned short* __restrict__ W1T, const unsigned short* __restrict__ W2T,
    const unsigned short* __restrict__ WavT, const float* __restrict__ adv,
    const float* __restrict__ ret, const float* __restrict__ sumP,
    float* __restrict__ lossP) {
    __shared__ __align__(16) unsigned short smA[2][128 * 32];   // 2 x 8KB
    __shared__ __align__(16) unsigned short smB[2][256 * 32];   // 2 x 16KB
    __shared__ __align__(16) unsigned short smH[128 * 256];     // 64KB
    __shared__ float red2[16];
    float* red = (float*)smH;   // stats scratch (smH dead until epilogue1)

    const int tid = threadIdx.x;
    const int wid = tid >> 6;
    const int lane = tid & 63;
    const int cl = lane & 15;
    const int gg = lane >> 4;
    const int mw = wid >> 2;
    const int nw = wid & 3;
    const int bm0 = blockIdx.x * 128;

    // A staging: thread -> 4 floats (16B coalesced), 8B bf16 ds_write
    const int arow = tid >> 3;                  // 0..127
    const int acol = (tid & 7) * 4;             // 0..28
    const int adst = arow * 32 +
        ((((acol >> 3) ^ ((arow >> 1) & 3)) << 3) | (acol & 4));
    const float* aSrc = obs + (size_t)(bm0 + arow) * 512 + acol;

    // B staging: thread -> one 16B chunk (coalesced), swizzled ds_write
    const int brow = tid >> 2;                  // 0..255
    const int bslot = tid & 3;
    const int bdst = brow * 32 + ((bslot ^ ((brow >> 1) & 3)) << 3);
    const unsigned short* b1Src = W1T + (size_t)brow * 512 + bslot * 8;
    const unsigned short* b2Src = W2T + (size_t)brow * 256 + bslot * 8;
    // Wav staging ([32][256], smH-style swizzle)
    const int wrow = tid >> 5;
    const int we = (tid & 31) * 8;
    const int wdst = wrow * 256 + (we ^ ((wrow & 7) << 3));

    // issue tile-0 loads early (stats reduction below covers latency)
    float4 areg = *(const float4*)aSrc;
    u16x8 breg = *(const u16x8*)b1Src;

    // ---- adv stats (folds gae4) ----
    float meanA, rstdA;
    {
        if (tid < 256) { red[tid] = sumP[2 * tid]; red[256 + tid] = sumP[2 * tid + 1]; }
        __syncthreads();
#pragma unroll
        for (int s = 128; s > 0; s >>= 1) {
            if (tid < s) { red[tid] += red[tid + s]; red[256 + tid] += red[256 + tid + s]; }
            __syncthreads();
        }
        meanA = red[0] * (1.0f / TT);
        float var = red[256] * (1.0f / TT) - meanA * meanA;
        rstdA = 1.0f / (sqrtf(fmaxf(var, 0.0f)) + 1e-8f);
        __syncthreads();
    }

    float b1v[4], b2v[4];
#pragma unroll
    for (int n = 0; n < 4; ++n) {
        int c = nw * 64 + n * 16 + cl;
        b1v[n] = b1[c];
        b2v[n] = b2[c];
    }
    const float bav = ba[cl];
    const float bc0 = bc[0];

    f32x4 acc[2][4];
#pragma unroll
    for (int m = 0; m < 2; ++m)
#pragma unroll
        for (int n = 0; n < 4; ++n) acc[m][n] = (f32x4){0.f, 0.f, 0.f, 0.f};

    auto writeA = [&](int buf) {
        u16x4 ac;
        ac[0] = f2bf(areg.x); ac[1] = f2bf(areg.y);
        ac[2] = f2bf(areg.z); ac[3] = f2bf(areg.w);
        *(u16x4*)&smA[buf][adst] = ac;
    };

    // prologue: write tile 0
    writeA(0);
    *(u16x8*)&smB[0][bdst] = breg;
    __syncthreads();

    // ---------------- GEMM1: hidden1 = tanh(obs @ W1 + b1), K=512, 16 tiles ----------------
#pragma unroll
    for (int t = 0; t < 16; ++t) {
        if (t < 15) {
            areg = *(const float4*)(aSrc + (t + 1) * 32);
            breg = *(const u16x8*)(b1Src + (t + 1) * 32);
        } else {
            breg = *(const u16x8*)b2Src;            // GEMM2 tile 0
        }
        bf16x8 av[2], bv[4];
#pragma unroll
        for (int m = 0; m < 2; ++m) {
            int ra = mw * 32 + m * 16 + cl;
            av[m] = *(const bf16x8*)&smA[t & 1][ra * 32 + ((gg ^ ((ra >> 1) & 3)) << 3)];
        }
#pragma unroll
        for (int n = 0; n < 4; ++n) {
            int rb = nw * 64 + n * 16 + cl;
            bv[n] = *(const bf16x8*)&smB[t & 1][rb * 32 + ((gg ^ ((rb >> 1) & 3)) << 3)];
        }
#pragma unroll
        for (int m = 0; m < 2; ++m)
#pragma unroll
            for (int n = 0; n < 4; ++n)
                acc[m][n] = __builtin_amdgcn_mfma_f32_16x16x32_bf16(av[m], bv[n], acc[m][n], 0, 0, 0);
        if (t < 15) writeA((t + 1) & 1);
        *(u16x8*)&smB[(t + 1) & 1][bdst] = breg;    // t==15 -> smB[0] = GEMM2 tile 0
        __syncthreads();
    }

    // epilogue 1: tanh -> smH (swizzled), reset acc
#pragma unroll
    for (int m = 0; m < 2; ++m)
#pragma unroll
        for (int n = 0; n < 4; ++n)
#pragma unroll
            for (int j = 0; j < 4; ++j) {
                int r = mw * 32 + m * 16 + gg * 4 + j;
                int c = nw * 64 + n * 16 + cl;
                smH[r * 256 + (c ^ ((r & 7) << 3))] = f2bf(fast_tanh(acc[m][n][j] + b1v[n]));
                acc[m][n][j] = 0.0f;
            }
    __syncthreads();   // hidden1 complete; smB[0] holds W2T tile 0

    // ---------------- GEMM2: hidden = tanh(hidden1 @ W2 + b2), K=256, 8 tiles ----------------
#pragma unroll
    for (int t = 0; t < 8; ++t) {
        if (t < 7) breg = *(const u16x8*)(b2Src + (t + 1) * 32);
        else       breg = *(const u16x8*)(WavT + wrow * 256 + we);   // head weights
        bf16x8 av[2], bv[4];
#pragma unroll
        for (int m = 0; m < 2; ++m) {
            int ra = mw * 32 + m * 16 + cl;
            av[m] = *(const bf16x8*)&smH[ra * 256 + ((t * 32 + gg * 8) ^ ((ra & 7) << 3))];
        }
#pragma unroll
        for (int n = 0; n < 4; ++n) {
            int rb = nw * 64 + n * 16 + cl;
            bv[n] = *(const bf16x8*)&smB[t & 1][rb * 32 + ((gg ^ ((rb >> 1) & 3)) << 3)];
        }
#pragma unroll
        for (int m = 0; m < 2; ++m)
#pragma unroll
            for (int n = 0; n < 4; ++n)
                acc[m][n] = __builtin_amdgcn_mfma_f32_16x16x32_bf16(av[m], bv[n], acc[m][n], 0, 0, 0);
        if (t < 7) *(u16x8*)&smB[(t + 1) & 1][bdst] = breg;
        else       *(u16x8*)&smB[0][wdst] = breg;   // Wav [32][256] into smB[0] region
        __syncthreads();
    }

    // epilogue 2: hidden -> smH (all GEMM2 smH reads done)
#pragma unroll
    for (int m = 0; m < 2; ++m)
#pragma unroll
        for (int n = 0; n < 4; ++n)
#pragma unroll
            for (int j = 0; j < 4; ++j) {
                int r = mw * 32 + m * 16 + gg * 4 + j;
                int c = nw * 64 + n * 16 + cl;
                smH[r * 256 + (c ^ ((r & 7) << 3))] = f2bf(fast_tanh(acc[m][n][j] + b2v[n]));
            }
    __syncthreads();   // hidden + head weights ready

    // ---------------- heads + loss: waves 0..7, wave wid owns rows [wid*16,+16) ----------------
    float lsum = 0.0f;
    if (wid < 8) {
        f32x4 acc_a = {0.f, 0.f, 0.f, 0.f}, acc_v = {0.f, 0.f, 0.f, 0.f};
#pragma unroll
        for (int kk = 0; kk < 8; ++kk) {
            int r = wid * 16 + cl;
            bf16x8 av = *(const bf16x8*)&smH[r * 256 + ((kk * 32 + gg * 8) ^ ((r & 7) << 3))];
            int ra2 = cl;
            bf16x8 bva = *(const bf16x8*)&smB[0][ra2 * 256 + ((kk * 32 + gg * 8) ^ ((ra2 & 7) << 3))];
            int rv = 16 + cl;
            bf16x8 bvv = *(const bf16x8*)&smB[0][rv * 256 + ((kk * 32 + gg * 8) ^ ((rv & 7) << 3))];
            acc_a = __builtin_amdgcn_mfma_f32_16x16x32_bf16(av, bva, acc_a, 0, 0, 0);
            acc_v = __builtin_amdgcn_mfma_f32_16x16x32_bf16(av, bvv, acc_v, 0, 0, 0);
        }

        const int t0 = bm0 + wid * 16;
#pragma unroll
        for (int j = 0; j < 4; ++j) {
            int t = t0 + gg * 4 + j;
            float lg = acc_a[j] + bav;
            float mx = lg;
#pragma unroll
            for (int dd = 1; dd < 16; dd <<= 1) mx = fmaxf(mx, __shfl_xor(mx, dd));
            float ex = __expf(lg - mx);
            float se = ex;
#pragma unroll
            for (int dd = 1; dd < 16; dd <<= 1) se += __shfl_xor(se, dd);
            float ls = __logf(se);
            float lp = lg - mx - ls;
            float pl = __expf(lp) * lp;
            float ent = pl;
#pragma unroll
            for (int dd = 1; dd < 16; dd <<= 1) ent += __shfl_xor(ent, dd);
            ent = -ent;
            int act = actions[t];
            float newlp = __shfl(lp, (lane & 48) | act);
            float val = __shfl(acc_v[j], lane & 48) + bc0;

            float lpo = logprobs[t];
            float at = (adv[t] - meanA) * rstdA;
            float rt = ret[t];
            float vo = values[t];
            float ratio = __expf(newlp - lpo);
            float rcl = fminf(fmaxf(ratio, 0.8f), 1.2f);
            float pg = fmaxf(-at * ratio, -at * rcl);
            float vcl = vo + fminf(fmaxf(val - vo, -0.2f), 0.2f);
            float dv = val - rt, dvc = vcl - rt;
            float vl = fmaxf(dv * dv, dvc * dvc);
            if (cl == 0) lsum += pg - 0.01f * ent + 0.25f * vl;
        }
        lsum += __shfl_xor(lsum, 16);
        lsum += __shfl_xor(lsum, 32);
    }
    if (wid < 8 && lane == 0) red2[wid] = lsum;
    __syncthreads();
    if (tid == 0) {
        float s = 0.0f;
#pragma unroll
        for (int w = 0; w < 8; ++w) s += red2[w];
        lossP[blockIdx.x] = s;
    }
}

__global__ void k_final(const float* __restrict__ lossP, float* __restrict__ out) {
    __shared__ float s[256];
    int i = threadIdx.x;
    s[i] = lossP[i] + lossP[i + 256];
    __syncthreads();
#pragma unroll
    for (int st = 128; st > 0; st >>= 1) {
        if (i < st) s[i] += s[i + st];
        __syncthreads();
    }
    if (i == 0) out[0] = s[0] * (1.0f / TT);
}

extern "C" void kernel_launch(void* const* d_in, const int* in_sizes, int n_in,
                              void* d_out, int out_size, void* d_ws, size_t ws_size,
                              hipStream_t stream) {
    const float* obs      = (const float*)d_in[0];
    const int*   actions  = (const int*)d_in[1];
    const float* logprobs = (const float*)d_in[2];
    const float* rewards  = (const float*)d_in[3];
    const float* terms    = (const float*)d_in[4];
    const float* values   = (const float*)d_in[5];
    const float* W1 = (const float*)d_in[6];
    const float* b1 = (const float*)d_in[7];
    const float* W2 = (const float*)d_in[8];
    const float* b2 = (const float*)d_in[9];
    const float* Wa = (const float*)d_in[10];
    const float* ba = (const float*)d_in[11];
    const float* Wc = (const float*)d_in[12];
    const float* bc = (const float*)d_in[13];

    char* ws = (char*)d_ws;
    unsigned short* W1T  = (unsigned short*)(ws + 0);        // 262144 B
    unsigned short* W2T  = (unsigned short*)(ws + 262144);   // 131072 B
    unsigned short* WavT = (unsigned short*)(ws + 393216);   // 16384 B
    float* advp  = (float*)(ws + 409600);                    // 262144 B
    float* retp  = (float*)(ws + 671744);                    // 262144 B
    float* aggC  = (float*)(ws + 933888);                    // 1024 B
    float* aggD  = (float*)(ws + 934912);                    // 1024 B
    float* sumP  = (float*)(ws + 936960);                    // 2048 B
    float* lossP = (float*)(ws + 939072);                    // 2048 B

    k_prep_gae1<<<1056, 256, 0, stream>>>(W1, W2, Wa, Wc, W1T, W2T, WavT,
                                          rewards, terms, values, aggC, aggD);
    k_gae3<<<256, 256, 0, stream>>>(rewards, terms, values, aggC, aggD, advp, retp, sumP);
    k_mlp<<<512, 1024, 0, stream>>>(obs, actions, logprobs, values, b1, b2, ba, bc,
                                    W1T, W2T, WavT, advp, retp, sumP, lossP);
    k_final<<<1, 256, 0, stream>>>(lossP, (float*)d_out);
}

// Round 7
// 65.905 us; speedup vs baseline: 2.6769x; 1.1124x over previous
//
#include <hip/hip_runtime.h>

// PPO loss fused pipeline for MI355X (gfx950).
// R6: occupancy-first k_mlp: 1024 blocks x 512 thr (8 waves), 64 rows/block,
// wave tile 64x32 (acc[4][2]). LDS 72KB -> 2 blocks/CU (desynced blocks cover
// each other's barrier drains, m97/m114 mechanism). B staging via
// global_load_lds from PRE-SWIZZLED weight layouts (k_prep bakes transpose +
// tile + XOR swizzle); A reg-staged fp32->bf16.

#define TT 65536

typedef float f32x4 __attribute__((ext_vector_type(4)));
typedef __bf16 bf16x8 __attribute__((ext_vector_type(8)));
typedef unsigned short u16x8 __attribute__((ext_vector_type(8)));
typedef unsigned short u16x4 __attribute__((ext_vector_type(4)));

__device__ __forceinline__ unsigned short f2bf(float f) {
    unsigned int u = __float_as_uint(f);
    unsigned int r = (u + 0x7fffu + ((u >> 16) & 1u)) >> 16;
    return (unsigned short)r;
}

// branch-free tanh: 1 - 2/(e^{2x}+1)
__device__ __forceinline__ float fast_tanh(float x) {
    float e = __expf(2.0f * x);
    return fmaf(-2.0f, __builtin_amdgcn_rcpf(e + 1.0f), 1.0f);
}

__device__ __forceinline__ void async_lds16(void* lds, const void* g) {
    __builtin_amdgcn_global_load_lds(
        (const __attribute__((address_space(1))) unsigned int*)g,
        (__attribute__((address_space(3))) unsigned int*)lds, 16, 0, 0);
}

// ---------------- GAE affine suffix scan ----------------
__device__ __forceinline__ void suffix_scan256(float* sC, float* sD, int i) {
    float c = sC[i], d = sD[i];
#pragma unroll
    for (int s = 1; s < 256; s <<= 1) {
        float c2 = 1.0f, d2 = 0.0f;
        if (i + s < 256) { c2 = sC[i + s]; d2 = sD[i + s]; }
        __syncthreads();
        d = d + c * d2;
        c = c * c2;
        sC[i] = c; sD[i] = d;
        __syncthreads();
    }
}

__device__ __forceinline__ void gae_cd(const float* rewards, const float* terms,
                                       const float* values, int t, float* c, float* d) {
    float nt = 1.0f - terms[t];
    float nv = (t + 1 < TT) ? values[t + 1] : 0.0f;
    *d = rewards[t] + 0.99f * nv * nt - values[t];
    *c = 0.99f * 0.95f * nt;
}

// ---------------- fused prep + gae1 ----------------
// Pre-swizzled weight layouts for global_load_lds (linear DMA -> swizzled LDS):
//   W1T_sw/W2T_sw: per K-tile kt (8192 elems): chunk L in [0,1024), elem e:
//     row = L>>2, p = L&3, k = kt*32 + ((p ^ ((row>>1)&3))<<3) + e
//     value = W[k][row]   (i.e. transposed)
//   WavT_sw (8192 elems): L in [0,1024): row = L>>5, ec = (L&31)<<3,
//     k = (ec ^ ((row&7)<<3)) + e; rows 0-15 = Wa^T, 16 = Wc^T, 17-31 = 0.
__global__ void k_prep_gae1(const float* __restrict__ W1, const float* __restrict__ W2,
                            const float* __restrict__ Wa, const float* __restrict__ Wc,
                            unsigned short* __restrict__ W1T, unsigned short* __restrict__ W2T,
                            unsigned short* __restrict__ WavT,
                            const float* __restrict__ rewards, const float* __restrict__ terms,
                            const float* __restrict__ values, float* __restrict__ aggC,
                            float* __restrict__ aggD) {
    if (blockIdx.x < 800) {
        int idx = blockIdx.x * 256 + threadIdx.x;
        if (idx < 131072) {
            int kt = idx >> 13;
            int L = (idx & 8191) >> 3, e = idx & 7;
            int row = L >> 2, p = L & 3;
            int k = kt * 32 + (((p ^ ((row >> 1) & 3)) << 3) | e);
            W1T[idx] = f2bf(W1[k * 256 + row]);
        } else if (idx < 196608) {
            int i = idx - 131072;
            int kt = i >> 13;
            int L = (i & 8191) >> 3, e = i & 7;
            int row = L >> 2, p = L & 3;
            int k = kt * 32 + (((p ^ ((row >> 1) & 3)) << 3) | e);
            W2T[i] = f2bf(W2[k * 256 + row]);
        } else if (idx < 204800) {
            int i = idx - 196608;
            int L = i >> 3, e = i & 7;
            int row = L >> 5, ec = (L & 31) << 3;
            int k = ((ec ^ ((row & 7) << 3)) | e);
            float v = (row < 16) ? Wa[k * 16 + row] : ((row == 16) ? Wc[k] : 0.0f);
            WavT[i] = f2bf(v);
        }
        return;
    }
    __shared__ float sC[256], sD[256];
    int i = threadIdx.x;
    int b = blockIdx.x - 800;
    int t = b * 256 + i;
    float c, d;
    gae_cd(rewards, terms, values, t, &c, &d);
    sC[i] = c; sD[i] = d;
    __syncthreads();
    suffix_scan256(sC, sD, i);
    if (i == 0) { aggC[b] = sC[0]; aggD[b] = sD[0]; }
}

// ---------------- gae3: carry + adv/ret + per-block sum partials ----------------
__global__ void k_gae3(const float* __restrict__ rewards, const float* __restrict__ terms,
                       const float* __restrict__ values, const float* __restrict__ aggC,
                       const float* __restrict__ aggD, float* __restrict__ adv,
                       float* __restrict__ ret, float* __restrict__ sumP) {
    __shared__ float sC[256], sD[256];
    int i = threadIdx.x, b = blockIdx.x;
    sC[i] = aggC[i]; sD[i] = aggD[i];
    __syncthreads();
    suffix_scan256(sC, sD, i);
    float carry = (b < 255) ? sD[b + 1] : 0.0f;
    __syncthreads();

    int t = b * 256 + i;
    float c, d;
    gae_cd(rewards, terms, values, t, &c, &d);
    sC[i] = c; sD[i] = d;
    __syncthreads();
    suffix_scan256(sC, sD, i);
    float a = sD[i] + sC[i] * carry;
    adv[t] = a;
    ret[t] = a + values[t];
    __syncthreads();
    sC[i] = a; sD[i] = a * a;
    __syncthreads();
#pragma unroll
    for (int s = 128; s > 0; s >>= 1) {
        if (i < s) { sC[i] += sC[i + s]; sD[i] += sD[i + s]; }
        __syncthreads();
    }
    if (i == 0) { sumP[2 * b] = sC[0]; sumP[2 * b + 1] = sD[0]; }
}

// ---------------- fused MLP + heads + loss (64 rows/block, 8 waves) ----------------
// Wave tile 64 rows x 32 cols: col offset = wid*32; acc[4][2].
// LDS (72KB): [0,32K) B dbuf (2x16K, shared GEMM1/GEMM2/heads),
//             [32K,40K) A dbuf (2x4K), [40K,72K) smH [64][256].
// Staged B/A tiles [R][32]: 16B slot' = slot ^ ((row>>1)&3).
// smH swizzle: elem' = elem ^ ((row&7)<<3).
__global__ __launch_bounds__(512, 4) void k_mlp(
    const float* __restrict__ obs, const int* __restrict__ actions,
    const float* __restrict__ logprobs, const float* __restrict__ values,
    const float* __restrict__ b1, const float* __restrict__ b2,
    const float* __restrict__ ba, const float* __restrict__ bc,
    const unsigned short* __restrict__ W1T, const unsigned short* __restrict__ W2T,
    const unsigned short* __restrict__ WavT, const float* __restrict__ adv,
    const float* __restrict__ ret, const float* __restrict__ sumP,
    float* __restrict__ lossP) {
    __shared__ __align__(16) unsigned char SM[73728];
    unsigned short* smB = (unsigned short*)SM;                   // 2 x 8192 elems
    unsigned short* smA = (unsigned short*)(SM + 32768);         // 2 x 2048 elems
    unsigned short* smH = (unsigned short*)(SM + 40960);         // [64][256]
    float* red = (float*)(SM + 40960);                           // stats scratch (pre-GEMM)
    float* red2 = (float*)(SM + 32768);                          // loss scratch (post-GEMM)

    const int tid = threadIdx.x;
    const int wid = tid >> 6;
    const int lane = tid & 63;
    const int cl = lane & 15;
    const int gg = lane >> 4;
    const int bm0 = blockIdx.x * 64;

    // A staging: 64x32 fp32, thread -> 4 floats (16B coalesced)
    const int arow = tid >> 3;                  // 0..63
    const int acol = (tid & 7) * 4;             // 0,4,..,28
    const int adst = arow * 32 +
        ((((acol >> 3) ^ ((arow >> 1) & 3)) << 3) | (acol & 4));
    const float* aSrc = obs + (size_t)(bm0 + arow) * 512 + acol;

    // B DMA: wave wid covers chunks {wid*2, wid*2+1} of 1KB
    // issue tile-0 loads early (stats reduce covers the latency)
    float4 areg = *(const float4*)aSrc;
#pragma unroll
    for (int c = 0; c < 2; ++c) {
        int chunk = wid * 2 + c;
        async_lds16(&smB[chunk * 512], W1T + chunk * 512 + lane * 8);
    }

    // ---- adv stats (folds gae4); scratch in smH region ----
    float meanA, rstdA;
    {
        if (tid < 256) { red[tid] = sumP[2 * tid]; red[256 + tid] = sumP[2 * tid + 1]; }
        __syncthreads();
#pragma unroll
        for (int s = 128; s > 0; s >>= 1) {
            if (tid < s) { red[tid] += red[tid + s]; red[256 + tid] += red[256 + tid + s]; }
            __syncthreads();
        }
        meanA = red[0] * (1.0f / TT);
        float var = red[256] * (1.0f / TT) - meanA * meanA;
        rstdA = 1.0f / (sqrtf(fmaxf(var, 0.0f)) + 1e-8f);
        __syncthreads();
    }

    float b1v[2], b2v[2];
#pragma unroll
    for (int n = 0; n < 2; ++n) {
        int c = wid * 32 + n * 16 + cl;
        b1v[n] = b1[c];
        b2v[n] = b2[c];
    }
    const float bav = ba[cl];
    const float bc0 = bc[0];

    f32x4 acc[4][2];
#pragma unroll
    for (int m = 0; m < 4; ++m)
#pragma unroll
        for (int n = 0; n < 2; ++n) acc[m][n] = (f32x4){0.f, 0.f, 0.f, 0.f};

    auto writeA = [&](int buf) {
        u16x4 ac;
        ac[0] = f2bf(areg.x); ac[1] = f2bf(areg.y);
        ac[2] = f2bf(areg.z); ac[3] = f2bf(areg.w);
        *(u16x4*)&smA[buf * 2048 + adst] = ac;
    };

    // prologue: A tile 0 into LDS
    writeA(0);
    __syncthreads();   // also drains B tile-0 DMA

    // ---------------- GEMM1: hidden1 = tanh(obs @ W1 + b1), K=512, 16 tiles ----------------
#pragma unroll
    for (int t = 0; t < 16; ++t) {
        // stage t+1 (B via DMA from pre-swizzled layout; A via regs)
        const unsigned short* bsrc = (t < 15) ? (W1T + (t + 1) * 8192) : W2T;
#pragma unroll
        for (int c = 0; c < 2; ++c) {
            int chunk = wid * 2 + c;
            async_lds16(&smB[((t + 1) & 1) * 8192 + chunk * 512], bsrc + chunk * 512 + lane * 8);
        }
        if (t < 15) areg = *(const float4*)(aSrc + (t + 1) * 32);

        bf16x8 av[4], bv[2];
#pragma unroll
        for (int m = 0; m < 4; ++m) {
            int ra = m * 16 + cl;
            av[m] = *(const bf16x8*)&smA[(t & 1) * 2048 + ra * 32 + ((gg ^ ((ra >> 1) & 3)) << 3)];
        }
#pragma unroll
        for (int n = 0; n < 2; ++n) {
            int rb = wid * 32 + n * 16 + cl;
            bv[n] = *(const bf16x8*)&smB[(t & 1) * 8192 + rb * 32 + ((gg ^ ((rb >> 1) & 3)) << 3)];
        }
#pragma unroll
        for (int m = 0; m < 4; ++m)
#pragma unroll
            for (int n = 0; n < 2; ++n)
                acc[m][n] = __builtin_amdgcn_mfma_f32_16x16x32_bf16(av[m], bv[n], acc[m][n], 0, 0, 0);
        if (t < 15) writeA((t + 1) & 1);
        __syncthreads();
    }

    // epilogue 1: tanh -> smH (swizzled), reset acc
#pragma unroll
    for (int m = 0; m < 4; ++m)
#pragma unroll
        for (int n = 0; n < 2; ++n)
#pragma unroll
            for (int j = 0; j < 4; ++j) {
                int r = m * 16 + gg * 4 + j;
                int c = wid * 32 + n * 16 + cl;
                smH[r * 256 + (c ^ ((r & 7) << 3))] = f2bf(fast_tanh(acc[m][n][j] + b1v[n]));
                acc[m][n][j] = 0.0f;
            }
    __syncthreads();   // hidden1 complete; smB buf0 holds W2T tile 0

    // ---------------- GEMM2: hidden = tanh(hidden1 @ W2 + b2), K=256, 8 tiles ----------------
#pragma unroll
    for (int t = 0; t < 8; ++t) {
        const unsigned short* bsrc = (t < 7) ? (W2T + (t + 1) * 8192) : WavT;
#pragma unroll
        for (int c = 0; c < 2; ++c) {
            int chunk = wid * 2 + c;
            async_lds16(&smB[((t + 1) & 1) * 8192 + chunk * 512], bsrc + chunk * 512 + lane * 8);
        }
        bf16x8 av[4], bv[2];
#pragma unroll
        for (int m = 0; m < 4; ++m) {
            int ra = m * 16 + cl;
            av[m] = *(const bf16x8*)&smH[ra * 256 + ((t * 32 + gg * 8) ^ ((ra & 7) << 3))];
        }
#pragma unroll
        for (int n = 0; n < 2; ++n) {
            int rb = wid * 32 + n * 16 + cl;
            bv[n] = *(const bf16x8*)&smB[(t & 1) * 8192 + rb * 32 + ((gg ^ ((rb >> 1) & 3)) << 3)];
        }
#pragma unroll
        for (int m = 0; m < 4; ++m)
#pragma unroll
            for (int n = 0; n < 2; ++n)
                acc[m][n] = __builtin_amdgcn_mfma_f32_16x16x32_bf16(av[m], bv[n], acc[m][n], 0, 0, 0);
        __syncthreads();
    }

    // epilogue 2: hidden -> smH; smB buf0 holds WavT [32][256] (smH-style swizzle)
#pragma unroll
    for (int m = 0; m < 4; ++m)
#pragma unroll
        for (int n = 0; n < 2; ++n)
#pragma unroll
            for (int j = 0; j < 4; ++j) {
                int r = m * 16 + gg * 4 + j;
                int c = wid * 32 + n * 16 + cl;
                smH[r * 256 + (c ^ ((r & 7) << 3))] = f2bf(fast_tanh(acc[m][n][j] + b2v[n]));
            }
    __syncthreads();

    // ---------------- heads + loss: waves 0..3 own rows [wid*16,+16) ----------------
    float lsum = 0.0f;
    if (wid < 4) {
        f32x4 acc_a = {0.f, 0.f, 0.f, 0.f}, acc_v = {0.f, 0.f, 0.f, 0.f};
#pragma unroll
        for (int kk = 0; kk < 8; ++kk) {
            int r = wid * 16 + cl;
            bf16x8 av = *(const bf16x8*)&smH[r * 256 + ((kk * 32 + gg * 8) ^ ((r & 7) << 3))];
            int ra2 = cl;
            bf16x8 bva = *(const bf16x8*)&smB[ra2 * 256 + ((kk * 32 + gg * 8) ^ ((ra2 & 7) << 3))];
            int rv = 16 + cl;
            bf16x8 bvv = *(const bf16x8*)&smB[rv * 256 + ((kk * 32 + gg * 8) ^ ((rv & 7) << 3))];
            acc_a = __builtin_amdgcn_mfma_f32_16x16x32_bf16(av, bva, acc_a, 0, 0, 0);
            acc_v = __builtin_amdgcn_mfma_f32_16x16x32_bf16(av, bvv, acc_v, 0, 0, 0);
        }

        const int t0 = bm0 + wid * 16;
#pragma unroll
        for (int j = 0; j < 4; ++j) {
            int t = t0 + gg * 4 + j;
            float lg = acc_a[j] + bav;
            float mx = lg;
#pragma unroll
            for (int dd = 1; dd < 16; dd <<= 1) mx = fmaxf(mx, __shfl_xor(mx, dd));
            float ex = __expf(lg - mx);
            float se = ex;
#pragma unroll
            for (int dd = 1; dd < 16; dd <<= 1) se += __shfl_xor(se, dd);
            float ls = __logf(se);
            float lp = lg - mx - ls;
            float pl = __expf(lp) * lp;
            float ent = pl;
#pragma unroll
            for (int dd = 1; dd < 16; dd <<= 1) ent += __shfl_xor(ent, dd);
            ent = -ent;
            int act = actions[t];
            float newlp = __shfl(lp, (lane & 48) | act);
            float val = __shfl(acc_v[j], lane & 48) + bc0;

            float lpo = logprobs[t];
            float at = (adv[t] - meanA) * rstdA;
            float rt = ret[t];
            float vo = values[t];
            float ratio = __expf(newlp - lpo);
            float rcl = fminf(fmaxf(ratio, 0.8f), 1.2f);
            float pg = fmaxf(-at * ratio, -at * rcl);
            float vcl = vo + fminf(fmaxf(val - vo, -0.2f), 0.2f);
            float dv = val - rt, dvc = vcl - rt;
            float vl = fmaxf(dv * dv, dvc * dvc);
            if (cl == 0) lsum += pg - 0.01f * ent + 0.25f * vl;
        }
        lsum += __shfl_xor(lsum, 16);
        lsum += __shfl_xor(lsum, 32);
    }
    __syncthreads();   // heads' smB reads done; smA region reusable as red2
    if (wid < 4 && lane == 0) red2[wid] = lsum;
    __syncthreads();
    if (tid == 0) lossP[blockIdx.x] = red2[0] + red2[1] + red2[2] + red2[3];
}

__global__ void k_final(const float* __restrict__ lossP, float* __restrict__ out) {
    __shared__ float s[256];
    int i = threadIdx.x;
    s[i] = lossP[i] + lossP[i + 256] + lossP[i + 512] + lossP[i + 768];
    __syncthreads();
#pragma unroll
    for (int st = 128; st > 0; st >>= 1) {
        if (i < st) s[i] += s[i + st];
        __syncthreads();
    }
    if (i == 0) out[0] = s[0] * (1.0f / TT);
}

extern "C" void kernel_launch(void* const* d_in, const int* in_sizes, int n_in,
                              void* d_out, int out_size, void* d_ws, size_t ws_size,
                              hipStream_t stream) {
    const float* obs      = (const float*)d_in[0];
    const int*   actions  = (const int*)d_in[1];
    const float* logprobs = (const float*)d_in[2];
    const float* rewards  = (const float*)d_in[3];
    const float* terms    = (const float*)d_in[4];
    const float* values   = (const float*)d_in[5];
    const float* W1 = (const float*)d_in[6];
    const float* b1 = (const float*)d_in[7];
    const float* W2 = (const float*)d_in[8];
    const float* b2 = (const float*)d_in[9];
    const float* Wa = (const float*)d_in[10];
    const float* ba = (const float*)d_in[11];
    const float* Wc = (const float*)d_in[12];
    const float* bc = (const float*)d_in[13];

    char* ws = (char*)d_ws;
    unsigned short* W1T  = (unsigned short*)(ws + 0);        // 262144 B
    unsigned short* W2T  = (unsigned short*)(ws + 262144);   // 131072 B
    unsigned short* WavT = (unsigned short*)(ws + 393216);   // 16384 B
    float* advp  = (float*)(ws + 409600);                    // 262144 B
    float* retp  = (float*)(ws + 671744);                    // 262144 B
    float* aggC  = (float*)(ws + 933888);                    // 1024 B
    float* aggD  = (float*)(ws + 934912);                    // 1024 B
    float* sumP  = (float*)(ws + 936960);                    // 2048 B
    float* lossP = (float*)(ws + 939072);                    // 4096 B

    k_prep_gae1<<<1056, 256, 0, stream>>>(W1, W2, Wa, Wc, W1T, W2T, WavT,
                                          rewards, terms, values, aggC, aggD);
    k_gae3<<<256, 256, 0, stream>>>(rewards, terms, values, aggC, aggD, advp, retp, sumP);
    k_mlp<<<1024, 512, 0, stream>>>(obs, actions, logprobs, values, b1, b2, ba, bc,
                                    W1T, W2T, WavT, advp, retp, sumP, lossP);
    k_final<<<1, 256, 0, stream>>>(lossP, (float*)d_out);
}